// Round 5
// baseline (233.411 us; speedup 1.0000x reference)
//
#include <hip/hip_runtime.h>
#include <math.h>

#define BB 4
#define SS 2048
#define DD 512
#define HH 8
#define HD 64
#define NTOK (BB*SS)
#define EPS 1e-5f
#define NE ((size_t)NTOK * DD)
#define WN ((size_t)DD * DD)
#define LOG2E 1.4426950408889634f

typedef _Float16 half8v __attribute__((ext_vector_type(8)));
typedef _Float16 half4v __attribute__((ext_vector_type(4)));
typedef _Float16 half2v __attribute__((ext_vector_type(2)));
typedef float f32x4 __attribute__((ext_vector_type(4)));

__device__ __forceinline__ float fast_exp2(float x) {
#if __has_builtin(__builtin_amdgcn_exp2f)
    return __builtin_amdgcn_exp2f(x);
#else
    return __expf(x * 0.6931471805599453f);
#endif
}

__device__ __forceinline__ half2v pack2(float a, float b) {
    return __builtin_bit_cast(half2v, __builtin_amdgcn_cvt_pkrtz(a, b));
}

__device__ __forceinline__ half4v pack4(float a, float b, float c, float d) {
    half2v lo = pack2(a, b);
    half2v hi = pack2(c, d);
    half4v r; r[0] = lo[0]; r[1] = lo[1]; r[2] = hi[0]; r[3] = hi[1];
    return r;
}

__device__ __forceinline__ void gload_lds16(const void* g, void* l) {
    __builtin_amdgcn_global_load_lds(
        (const __attribute__((address_space(1))) unsigned int*)g,
        (__attribute__((address_space(3))) unsigned int*)l, 16, 0, 0);
}

// ---------------- LayerNorm (optional residual, optional f16 copy) ----------
__global__ __launch_bounds__(256) void ln_kernel(const float* __restrict__ x,
                                                 const float* __restrict__ res,
                                                 const float* __restrict__ gamma,
                                                 const float* __restrict__ beta,
                                                 float* __restrict__ y,
                                                 _Float16* __restrict__ y16) {
    int row = blockIdx.x;
    const float* xr = x + (size_t)row * DD;
    int t = threadIdx.x;
    float2 v = ((const float2*)xr)[t];
    if (res) {
        float2 r = ((const float2*)(res + (size_t)row * DD))[t];
        v.x += r.x; v.y += r.y;
    }
    float s = v.x + v.y;
    float ss = v.x * v.x + v.y * v.y;
    #pragma unroll
    for (int off = 32; off; off >>= 1) {
        s  += __shfl_down(s,  off);
        ss += __shfl_down(ss, off);
    }
    __shared__ float ws0[4], ws1[4];
    int wid = t >> 6, lane = t & 63;
    if (lane == 0) { ws0[wid] = s; ws1[wid] = ss; }
    __syncthreads();
    __shared__ float mu_s, rstd_s;
    if (t == 0) {
        float S0 = ws0[0] + ws0[1] + ws0[2] + ws0[3];
        float S1 = ws1[0] + ws1[1] + ws1[2] + ws1[3];
        float mu = S0 * (1.0f / DD);
        float var = S1 * (1.0f / DD) - mu * mu;
        mu_s = mu;
        rstd_s = rsqrtf(var + EPS);
    }
    __syncthreads();
    float mu = mu_s, rstd = rstd_s;
    float2 g = ((const float2*)gamma)[t];
    float2 bb = ((const float2*)beta)[t];
    float2 o;
    o.x = (v.x - mu) * rstd * g.x + bb.x;
    o.y = (v.y - mu) * rstd * g.y + bb.y;
    if (y)   ((float2*)(y + (size_t)row * DD))[t] = o;
    if (y16) {
        *(half2v*)&y16[(size_t)row * DD + 2 * t] = pack2(o.x, o.y);
    }
}

// ---------------- casts ----------------
__global__ __launch_bounds__(256) void cast_qk(const float* __restrict__ a,
                                               const float* __restrict__ b,
                                               _Float16* __restrict__ dst) {
    size_t i = ((size_t)blockIdx.x * 256 + threadIdx.x) * 4;
    const float* src = (i < NE) ? (a + i) : (b + (i - NE));
    float4 v = *(const float4*)src;
    *(half4v*)(dst + i) = pack4(v.x, v.y, v.z, v.w);
}

__global__ __launch_bounds__(256) void cast_w(const float* __restrict__ W1,
                                              const float* __restrict__ W2,
                                              const float* __restrict__ W3,
                                              _Float16* __restrict__ dst) {
    size_t i = ((size_t)blockIdx.x * 256 + threadIdx.x) * 4;
    const float* src; float sc;
    if (i < WN)            { src = W1 + i;          sc = LOG2E; }  // fold log2e into Q
    else if (i < 2 * WN)   { src = W2 + (i - WN);   sc = 1.0f; }
    else                   { src = W3 + (i - 2*WN); sc = 1.0f; }
    float4 v = *(const float4*)src;
    *(half4v*)(dst + i) = pack4(v.x * sc, v.y * sc, v.z * sc, v.w * sc);
}

// ---------------- MFMA GEMM: all three projections in one launch ------------
// z=0 (q), z=1 (k): compute C^T = W.A^T  -> packed stores into [b,h,s,d]
// z=2 (v):          compute C   = A.W^T  -> packed stores into vt[b,h,d,s]
#define GBM 128
#define GBN 128
#define GBK 64
__global__ __launch_bounds__(256) void gemm_mfma(const _Float16* __restrict__ Aall,
                                                 const _Float16* __restrict__ Wall,
                                                 _Float16* __restrict__ Call,
                                                 _Float16* __restrict__ vtOut) {
    __shared__ __align__(16) _Float16 As[GBM * GBK];
    __shared__ __align__(16) _Float16 Ws[GBN * GBK];
    int z = blockIdx.z;
    bool isv = (z == 2);
    const _Float16* A = Aall + (size_t)z * NE;
    const _Float16* W = Wall + (size_t)z * WN;
    int t = threadIdx.x, w = t >> 6, lane = t & 63, q = lane >> 4, ln = lane & 15;
    int lrow = lane >> 3, lseg = lane & 7;
    int m0 = blockIdx.y * GBM, n0 = blockIdx.x * GBN;
    int wm = w & 1, wn = w >> 1;
    f32x4 acc[4][4];
    #pragma unroll
    for (int mt = 0; mt < 4; ++mt)
        #pragma unroll
        for (int nt = 0; nt < 4; ++nt)
            acc[mt][nt] = (f32x4){0.f, 0.f, 0.f, 0.f};

    int gs = lseg ^ lrow;
    for (int k0 = 0; k0 < DD; k0 += GBK) {
        #pragma unroll
        for (int p = 0; p < 4; ++p) {
            int r = w * 32 + p * 8 + lrow;
            gload_lds16(A + (size_t)(m0 + r) * DD + k0 + gs * 8,
                        As + (size_t)(w * 32 + p * 8) * GBK);
            gload_lds16(W + (size_t)(n0 + r) * DD + k0 + gs * 8,
                        Ws + (size_t)(w * 32 + p * 8) * GBK);
        }
        __syncthreads();
        #pragma unroll
        for (int kk = 0; kk < 2; ++kk) {
            int ch = ((4 * kk + q) ^ (ln & 7)) * 8;
            half8v af[4], wf[4];
            #pragma unroll
            for (int mt = 0; mt < 4; ++mt)
                af[mt] = *(half8v*)&As[(wm * 64 + mt * 16 + ln) * GBK + ch];
            #pragma unroll
            for (int nt = 0; nt < 4; ++nt)
                wf[nt] = *(half8v*)&Ws[(wn * 64 + nt * 16 + ln) * GBK + ch];
            if (!isv) {
                #pragma unroll
                for (int mt = 0; mt < 4; ++mt)
                    #pragma unroll
                    for (int nt = 0; nt < 4; ++nt)
                        acc[mt][nt] = __builtin_amdgcn_mfma_f32_16x16x32_f16(
                            wf[nt], af[mt], acc[mt][nt], 0, 0, 0);  // C^T
            } else {
                #pragma unroll
                for (int mt = 0; mt < 4; ++mt)
                    #pragma unroll
                    for (int nt = 0; nt < 4; ++nt)
                        acc[mt][nt] = __builtin_amdgcn_mfma_f32_16x16x32_f16(
                            af[mt], wf[nt], acc[mt][nt], 0, 0, 0);  // C
            }
        }
        __syncthreads();
    }
    if (!isv) {
        // rows(regs)=feature n, cols(lane)=token m
        _Float16* C = Call + (size_t)z * NE;
        #pragma unroll
        for (int mt = 0; mt < 4; ++mt) {
            int m = m0 + wm * 64 + mt * 16 + ln;
            int b = m >> 11, s = m & (SS - 1);
            #pragma unroll
            for (int nt = 0; nt < 4; ++nt) {
                int nb = n0 + wn * 64 + nt * 16 + q * 4;
                int h = nb >> 6, d0 = nb & 63;
                half4v pv = pack4(acc[mt][nt][0], acc[mt][nt][1],
                                  acc[mt][nt][2], acc[mt][nt][3]);
                *(half4v*)&C[((size_t)(b * HH + h) * SS + s) * HD + d0] = pv;
            }
        }
    } else {
        // rows(regs)=token m, cols(lane)=feature n -> vt[b,h,d,s]
        #pragma unroll
        for (int mt = 0; mt < 4; ++mt) {
            int mb = m0 + wm * 64 + mt * 16 + q * 4;
            int b = mb >> 11, s0 = mb & (SS - 1);
            #pragma unroll
            for (int nt = 0; nt < 4; ++nt) {
                int n = n0 + wn * 64 + nt * 16 + ln;
                int h = n >> 6, d = n & 63;
                half4v pv = pack4(acc[mt][nt][0], acc[mt][nt][1],
                                  acc[mt][nt][2], acc[mt][nt][3]);
                *(half4v*)&vtOut[((size_t)(b * HH + h) * HD + d) * SS + s0] = pv;
            }
        }
    }
}

// ---------------- Flash attention, S^T orientation, AJ=128 ------------------
#define AI 128
#define AJ 128
__global__ __launch_bounds__(256) void attn_mfma(const _Float16* __restrict__ qh,
                                                 const _Float16* __restrict__ kh,
                                                 const _Float16* __restrict__ vt,
                                                 float* __restrict__ out) {
    __shared__ __align__(16) _Float16 Qt[AJ * HD];   // 128 j-rows x 64 d (swizzled)
    __shared__ __align__(16) _Float16 Vs[HD * AJ];   // 64 d-rows x 128 j (swizzled)
    __shared__ __align__(16) _Float16 Ps[AI * AJ];   // 128 i-rows x 128 j (swizzled)
    int t = threadIdx.x, w = t >> 6, lane = t & 63, q = lane >> 4, ln = lane & 15;
    int i0 = blockIdx.x * AI;
    int bh = blockIdx.y, b = bh >> 3, h = bh & 7;
    const _Float16* Kb = kh + (size_t)bh * SS * HD;
    const _Float16* Qb = qh + (size_t)bh * SS * HD;
    const _Float16* Vb = vt + (size_t)bh * HD * SS;

    half8v kf[2][2];
    #pragma unroll
    for (int nt = 0; nt < 2; ++nt)
        #pragma unroll
        for (int kk = 0; kk < 2; ++kk)
            kf[nt][kk] = *(const half8v*)&Kb[(size_t)(i0 + w * 32 + nt * 16 + ln) * HD
                                             + kk * 32 + q * 8];

    f32x4 oacc[4][2], lacc[2];
    float m_run[2];
    #pragma unroll
    for (int nt = 0; nt < 2; ++nt) {
        m_run[nt] = -3.0e38f;
        lacc[nt] = (f32x4){0.f, 0.f, 0.f, 0.f};
        #pragma unroll
        for (int mtd = 0; mtd < 4; ++mtd) oacc[mtd][nt] = (f32x4){0.f, 0.f, 0.f, 0.f};
    }
    half8v ones;
    #pragma unroll
    for (int e = 0; e < 8; ++e) ones[e] = (_Float16)1.0f;
    const f32x4 zf = (f32x4){0.f, 0.f, 0.f, 0.f};

    for (int j0 = 0; j0 < SS; j0 += AJ) {
        // stage Q(128x64) and V^T(64x128), async, XOR-chunk-swizzled
        #pragma unroll
        for (int p = 0; p < 4; ++p) {
            int idx = p * 256 + t;
            int rq = idx >> 3, cq = idx & 7;
            gload_lds16(Qb + (size_t)(j0 + rq) * HD + (cq ^ (rq & 7)) * 8,
                        Qt + (size_t)(p * 256 + w * 64) * 8);
            int rv = idx >> 4, cv = idx & 15;
            int csv = (cv & 8) | ((cv & 7) ^ (rv & 7));
            gload_lds16(Vb + (size_t)rv * SS + j0 + csv * 8,
                        Vs + (size_t)(p * 256 + w * 64) * 8);
        }
        __syncthreads();

        // ---- S^T = Q.K^T : M=j(128), N=i(32/wave), K=d(64) ----
        f32x4 sacc[8][2];
        #pragma unroll
        for (int mt = 0; mt < 8; ++mt) {
            half8v qf = *(half8v*)&Qt[(mt * 16 + ln) * HD + (q ^ (ln & 7)) * 8];
            sacc[mt][0] = __builtin_amdgcn_mfma_f32_16x16x32_f16(qf, kf[0][0], zf, 0, 0, 0);
            sacc[mt][1] = __builtin_amdgcn_mfma_f32_16x16x32_f16(qf, kf[1][0], zf, 0, 0, 0);
        }
        #pragma unroll
        for (int mt = 0; mt < 8; ++mt) {
            half8v qf = *(half8v*)&Qt[(mt * 16 + ln) * HD + ((4 + q) ^ (ln & 7)) * 8];
            sacc[mt][0] = __builtin_amdgcn_mfma_f32_16x16x32_f16(qf, kf[0][1], sacc[mt][0], 0, 0, 0);
            sacc[mt][1] = __builtin_amdgcn_mfma_f32_16x16x32_f16(qf, kf[1][1], sacc[mt][1], 0, 0, 0);
        }

        // ---- online softmax over j (rows) ----
        float mn[2];
        #pragma unroll
        for (int nt = 0; nt < 2; ++nt) {
            float mx = sacc[0][nt][0];
            #pragma unroll
            for (int mt = 0; mt < 8; ++mt)
                #pragma unroll
                for (int r = 0; r < 4; ++r) mx = fmaxf(mx, sacc[mt][nt][r]);
            mx = fmaxf(mx, __shfl_xor(mx, 16));
            mx = fmaxf(mx, __shfl_xor(mx, 32));
            mn[nt] = fmaxf(m_run[nt], mx);
        }
        if (__any((mn[0] > m_run[0]) || (mn[1] > m_run[1]))) {
            float a0 = fast_exp2(m_run[0] - mn[0]);
            float a1 = fast_exp2(m_run[1] - mn[1]);
            lacc[0] *= a0; lacc[1] *= a1;
            #pragma unroll
            for (int mtd = 0; mtd < 4; ++mtd) { oacc[mtd][0] *= a0; oacc[mtd][1] *= a1; }
        }
        m_run[0] = mn[0]; m_run[1] = mn[1];

        // ---- P = exp2(S^T - m), write to wave-private LDS rows ----
        #pragma unroll
        for (int nt = 0; nt < 2; ++nt) {
            int rp = w * 32 + nt * 16 + ln;
            #pragma unroll
            for (int mt = 0; mt < 8; ++mt) {
                float p0 = fast_exp2(sacc[mt][nt][0] - mn[nt]);
                float p1 = fast_exp2(sacc[mt][nt][1] - mn[nt]);
                float p2 = fast_exp2(sacc[mt][nt][2] - mn[nt]);
                float p3 = fast_exp2(sacc[mt][nt][3] - mn[nt]);
                int cw = mt * 2 + (q >> 1);
                int pos = (cw & 8) | ((cw & 7) ^ (ln & 7));
                *(half4v*)&Ps[(size_t)rp * AJ + pos * 8 + (q & 1) * 4] =
                    pack4(p0, p1, p2, p3);
            }
        }

        // ---- O^T += V^T.P^T ; l += 1.P^T  (M=d / ones, N=i, K=j) ----
        #pragma unroll
        for (int ks = 0; ks < 4; ++ks) {
            int cd = ks * 4 + q;
            int pos = ((cd & 8) | ((cd & 7) ^ (ln & 7))) * 8;
            half8v pf0 = *(half8v*)&Ps[(size_t)(w * 32 + ln) * AJ + pos];
            half8v pf1 = *(half8v*)&Ps[(size_t)(w * 32 + 16 + ln) * AJ + pos];
            lacc[0] = __builtin_amdgcn_mfma_f32_16x16x32_f16(ones, pf0, lacc[0], 0, 0, 0);
            lacc[1] = __builtin_amdgcn_mfma_f32_16x16x32_f16(ones, pf1, lacc[1], 0, 0, 0);
            #pragma unroll
            for (int mtd = 0; mtd < 4; ++mtd) {
                half8v vf = *(half8v*)&Vs[(size_t)(mtd * 16 + ln) * AJ + pos];
                oacc[mtd][0] = __builtin_amdgcn_mfma_f32_16x16x32_f16(vf, pf0, oacc[mtd][0], 0, 0, 0);
                oacc[mtd][1] = __builtin_amdgcn_mfma_f32_16x16x32_f16(vf, pf1, oacc[mtd][1], 0, 0, 0);
            }
        }
        __syncthreads();
    }

    // ---- epilogue ----
    #pragma unroll
    for (int nt = 0; nt < 2; ++nt) {
        float inv = 1.0f / lacc[nt][0];
        int i = i0 + w * 32 + nt * 16 + ln;
        #pragma unroll
        for (int mtd = 0; mtd < 4; ++mtd) {
            float4 o;
            o.x = oacc[mtd][nt][0] * inv;
            o.y = oacc[mtd][nt][1] * inv;
            o.z = oacc[mtd][nt][2] * inv;
            o.w = oacc[mtd][nt][3] * inv;
            *(float4*)&out[(size_t)(b * SS + i) * DD + h * HD + mtd * 16 + q * 4] = o;
        }
    }
}

extern "C" void kernel_launch(void* const* d_in, const int* in_sizes, int n_in,
                              void* d_out, int out_size, void* d_ws, size_t ws_size,
                              hipStream_t stream) {
    const float* seq_k = (const float*)d_in[0];
    const float* seq_q = (const float*)d_in[1];
    const float* seq_v = (const float*)d_in[2];
    const float* W1    = (const float*)d_in[3];
    const float* W2    = (const float*)d_in[4];
    const float* W3    = (const float*)d_in[5];
    const float* gamma = (const float*)d_in[6];
    const float* beta  = (const float*)d_in[7];
    float* out = (float*)d_out;

    const size_t MB = 1024 * 1024;
    char* w8 = (char*)d_ws;
    float*    v_in = (float*)w8;                    // [0,16) MB fp32 residual
    _Float16* a16  = (_Float16*)(w8 + 16 * MB);     // q16,k16,v16 [16,40)
    _Float16* w16  = (_Float16*)(w8 + 40 * MB);     // [40,42)
    _Float16* qh   = (_Float16*)(w8 + 48 * MB);     // [48,56)
    _Float16* vt   = (_Float16*)(w8 + 64 * MB);     // [64,72)
    float*    ao   = (float*)(w8 + 16 * MB);        // aliases a16/w16 (dead post-gemm)

    _Float16* q16 = a16;
    _Float16* v16 = a16 + 2 * NE;
    _Float16* kh  = qh + NE;

    // 1. pre-LN on seq_v -> fp32 residual + f16 GEMM input
    hipLaunchKernelGGL(ln_kernel, dim3(NTOK), dim3(256), 0, stream,
                       seq_v, (const float*)nullptr, gamma, beta, v_in, v16);
    // 2. casts (q,k fused; W1..3 fused, W1 pre-scaled by log2e)
    hipLaunchKernelGGL(cast_qk, dim3((unsigned)(2 * NE / 1024)), dim3(256), 0, stream,
                       seq_q, seq_k, q16);
    hipLaunchKernelGGL(cast_w, dim3((unsigned)(3 * WN / 1024)), dim3(256), 0, stream,
                       W1, W2, W3, w16);
    // 3. projections: q,k -> head-split; v -> transposed vt directly
    hipLaunchKernelGGL(gemm_mfma, dim3(DD / GBN, NTOK / GBM, 3), dim3(256), 0, stream,
                       a16, w16, qh, vt);
    // 4. flash attention
    hipLaunchKernelGGL(attn_mfma, dim3(SS / AI, BB * HH), dim3(256), 0, stream,
                       qh, kh, vt, ao);
    // 5. residual + final LN
    hipLaunchKernelGGL(ln_kernel, dim3(NTOK), dim3(256), 0, stream,
                       ao, v_in, gamma, beta, out, (_Float16*)nullptr);
}

// Round 6
// 196.977 us; speedup vs baseline: 1.1850x; 1.1850x over previous
//
#include <hip/hip_runtime.h>
#include <math.h>

#define BB 4
#define SS 2048
#define DD 512
#define HH 8
#define HD 64
#define NTOK (BB*SS)
#define EPS 1e-5f
#define NE ((size_t)NTOK * DD)
#define WN ((size_t)DD * DD)
#define LOG2E 1.4426950408889634f

typedef _Float16 half8v __attribute__((ext_vector_type(8)));
typedef _Float16 half4v __attribute__((ext_vector_type(4)));
typedef _Float16 half2v __attribute__((ext_vector_type(2)));
typedef float f32x4 __attribute__((ext_vector_type(4)));

__device__ __forceinline__ float fast_exp2(float x) {
#if __has_builtin(__builtin_amdgcn_exp2f)
    return __builtin_amdgcn_exp2f(x);
#else
    return __expf(x * 0.6931471805599453f);
#endif
}

__device__ __forceinline__ half2v pack2(float a, float b) {
    return __builtin_bit_cast(half2v, __builtin_amdgcn_cvt_pkrtz(a, b));
}

__device__ __forceinline__ half4v pack4(float a, float b, float c, float d) {
    half2v lo = pack2(a, b);
    half2v hi = pack2(c, d);
    half4v r; r[0] = lo[0]; r[1] = lo[1]; r[2] = hi[0]; r[3] = hi[1];
    return r;
}

__device__ __forceinline__ void gload_lds16(const void* g, void* l) {
    __builtin_amdgcn_global_load_lds(
        (const __attribute__((address_space(1))) unsigned int*)g,
        (__attribute__((address_space(3))) unsigned int*)l, 16, 0, 0);
}

// ---------------- final LayerNorm (with residual) ----------------
__global__ __launch_bounds__(256) void ln_kernel(const float* __restrict__ x,
                                                 const float* __restrict__ res,
                                                 const float* __restrict__ gamma,
                                                 const float* __restrict__ beta,
                                                 float* __restrict__ y) {
    int row = blockIdx.x;
    const float* xr = x + (size_t)row * DD;
    int t = threadIdx.x;
    float2 v = ((const float2*)xr)[t];
    {
        float2 r = ((const float2*)(res + (size_t)row * DD))[t];
        v.x += r.x; v.y += r.y;
    }
    float s = v.x + v.y;
    float ss = v.x * v.x + v.y * v.y;
    #pragma unroll
    for (int off = 32; off; off >>= 1) {
        s  += __shfl_down(s,  off);
        ss += __shfl_down(ss, off);
    }
    __shared__ float ws0[4], ws1[4];
    int wid = t >> 6, lane = t & 63;
    if (lane == 0) { ws0[wid] = s; ws1[wid] = ss; }
    __syncthreads();
    __shared__ float mu_s, rstd_s;
    if (t == 0) {
        float S0 = ws0[0] + ws0[1] + ws0[2] + ws0[3];
        float S1 = ws1[0] + ws1[1] + ws1[2] + ws1[3];
        float mu = S0 * (1.0f / DD);
        float var = S1 * (1.0f / DD) - mu * mu;
        mu_s = mu;
        rstd_s = rsqrtf(var + EPS);
    }
    __syncthreads();
    float mu = mu_s, rstd = rstd_s;
    float2 g = ((const float2*)gamma)[t];
    float2 bb = ((const float2*)beta)[t];
    float2 o;
    o.x = (v.x - mu) * rstd * g.x + bb.x;
    o.y = (v.y - mu) * rstd * g.y + bb.y;
    ((float2*)(y + (size_t)row * DD))[t] = o;
}

// ---------------- prep: LN(seq_v) + cast q/k + cast W (fused) --------------
// blocks [0,8192): LN rows; [8192,16384): q/k cast; [16384,17152): W cast
__global__ __launch_bounds__(256) void prep_kernel(const float* __restrict__ seq_v,
                                                   const float* __restrict__ seq_q,
                                                   const float* __restrict__ seq_k,
                                                   const float* __restrict__ W1,
                                                   const float* __restrict__ W2,
                                                   const float* __restrict__ W3,
                                                   const float* __restrict__ gamma,
                                                   const float* __restrict__ beta,
                                                   float* __restrict__ v_in,
                                                   _Float16* __restrict__ v16,
                                                   _Float16* __restrict__ qk16,
                                                   _Float16* __restrict__ w16) {
    int bid = blockIdx.x;
    int t = threadIdx.x;
    if (bid < NTOK) {
        int row = bid;
        float2 v = ((const float2*)(seq_v + (size_t)row * DD))[t];
        float s = v.x + v.y;
        float ss = v.x * v.x + v.y * v.y;
        #pragma unroll
        for (int off = 32; off; off >>= 1) {
            s  += __shfl_down(s,  off);
            ss += __shfl_down(ss, off);
        }
        __shared__ float ws0[4], ws1[4];
        int wid = t >> 6, lane = t & 63;
        if (lane == 0) { ws0[wid] = s; ws1[wid] = ss; }
        __syncthreads();
        __shared__ float mu_s, rstd_s;
        if (t == 0) {
            float S0 = ws0[0] + ws0[1] + ws0[2] + ws0[3];
            float S1 = ws1[0] + ws1[1] + ws1[2] + ws1[3];
            float mu = S0 * (1.0f / DD);
            float var = S1 * (1.0f / DD) - mu * mu;
            mu_s = mu;
            rstd_s = rsqrtf(var + EPS);
        }
        __syncthreads();
        float mu = mu_s, rstd = rstd_s;
        float2 g = ((const float2*)gamma)[t];
        float2 bb = ((const float2*)beta)[t];
        float2 o;
        o.x = (v.x - mu) * rstd * g.x + bb.x;
        o.y = (v.y - mu) * rstd * g.y + bb.y;
        ((float2*)(v_in + (size_t)row * DD))[t] = o;
        *(half2v*)&v16[(size_t)row * DD + 2 * t] = pack2(o.x, o.y);
    } else if (bid < 2 * NTOK) {
        size_t i = ((size_t)(bid - NTOK) * 256 + t) * 4;
        const float* src = (i < NE) ? (seq_q + i) : (seq_k + (i - NE));
        float4 v = *(const float4*)src;
        *(half4v*)(qk16 + i) = pack4(v.x, v.y, v.z, v.w);
    } else {
        size_t i = ((size_t)(bid - 2 * NTOK) * 256 + t) * 4;
        const float* src; float sc;
        if (i < WN)          { src = W1 + i;            sc = LOG2E; }
        else if (i < 2 * WN) { src = W2 + (i - WN);     sc = 1.0f; }
        else                 { src = W3 + (i - 2 * WN); sc = 1.0f; }
        float4 v = *(const float4*)src;
        *(half4v*)(w16 + i) = pack4(v.x * sc, v.y * sc, v.z * sc, v.w * sc);
    }
}

// ---------------- MFMA GEMM: all three projections in one launch ------------
// z=0 (q), z=1 (k): compute C^T = W.A^T  -> packed stores into [b,h,s,d]
// z=2 (v):          compute C   = A.W^T  -> packed stores into vt[b,h,d,s]
#define GBM 128
#define GBN 128
#define GBK 64
__global__ __launch_bounds__(256) void gemm_mfma(const _Float16* __restrict__ Aall,
                                                 const _Float16* __restrict__ Wall,
                                                 _Float16* __restrict__ Call,
                                                 _Float16* __restrict__ vtOut) {
    __shared__ __align__(16) _Float16 As[GBM * GBK];
    __shared__ __align__(16) _Float16 Ws[GBN * GBK];
    int z = blockIdx.z;
    bool isv = (z == 2);
    const _Float16* A = Aall + (size_t)z * NE;
    const _Float16* W = Wall + (size_t)z * WN;
    int t = threadIdx.x, w = t >> 6, lane = t & 63, q = lane >> 4, ln = lane & 15;
    int lrow = lane >> 3, lseg = lane & 7;
    int m0 = blockIdx.y * GBM, n0 = blockIdx.x * GBN;
    int wm = w & 1, wn = w >> 1;
    f32x4 acc[4][4];
    #pragma unroll
    for (int mt = 0; mt < 4; ++mt)
        #pragma unroll
        for (int nt = 0; nt < 4; ++nt)
            acc[mt][nt] = (f32x4){0.f, 0.f, 0.f, 0.f};

    int gs = lseg ^ lrow;
    for (int k0 = 0; k0 < DD; k0 += GBK) {
        #pragma unroll
        for (int p = 0; p < 4; ++p) {
            int r = w * 32 + p * 8 + lrow;
            gload_lds16(A + (size_t)(m0 + r) * DD + k0 + gs * 8,
                        As + (size_t)(w * 32 + p * 8) * GBK);
            gload_lds16(W + (size_t)(n0 + r) * DD + k0 + gs * 8,
                        Ws + (size_t)(w * 32 + p * 8) * GBK);
        }
        __syncthreads();
        #pragma unroll
        for (int kk = 0; kk < 2; ++kk) {
            int ch = ((4 * kk + q) ^ (ln & 7)) * 8;
            half8v af[4], wf[4];
            #pragma unroll
            for (int mt = 0; mt < 4; ++mt)
                af[mt] = *(half8v*)&As[(wm * 64 + mt * 16 + ln) * GBK + ch];
            #pragma unroll
            for (int nt = 0; nt < 4; ++nt)
                wf[nt] = *(half8v*)&Ws[(wn * 64 + nt * 16 + ln) * GBK + ch];
            if (!isv) {
                #pragma unroll
                for (int mt = 0; mt < 4; ++mt)
                    #pragma unroll
                    for (int nt = 0; nt < 4; ++nt)
                        acc[mt][nt] = __builtin_amdgcn_mfma_f32_16x16x32_f16(
                            wf[nt], af[mt], acc[mt][nt], 0, 0, 0);  // C^T
            } else {
                #pragma unroll
                for (int mt = 0; mt < 4; ++mt)
                    #pragma unroll
                    for (int nt = 0; nt < 4; ++nt)
                        acc[mt][nt] = __builtin_amdgcn_mfma_f32_16x16x32_f16(
                            af[mt], wf[nt], acc[mt][nt], 0, 0, 0);  // C
            }
        }
        __syncthreads();
    }
    if (!isv) {
        // rows(regs)=feature n, cols(lane)=token m
        _Float16* C = Call + (size_t)z * NE;
        #pragma unroll
        for (int mt = 0; mt < 4; ++mt) {
            int m = m0 + wm * 64 + mt * 16 + ln;
            int b = m >> 11, s = m & (SS - 1);
            #pragma unroll
            for (int nt = 0; nt < 4; ++nt) {
                int nb = n0 + wn * 64 + nt * 16 + q * 4;
                int h = nb >> 6, d0 = nb & 63;
                half4v pv = pack4(acc[mt][nt][0], acc[mt][nt][1],
                                  acc[mt][nt][2], acc[mt][nt][3]);
                *(half4v*)&C[((size_t)(b * HH + h) * SS + s) * HD + d0] = pv;
            }
        }
    } else {
        // rows(regs)=token m, cols(lane)=feature n -> vt[b,h,d,s]
        #pragma unroll
        for (int mt = 0; mt < 4; ++mt) {
            int mb = m0 + wm * 64 + mt * 16 + q * 4;
            int b = mb >> 11, s0 = mb & (SS - 1);
            #pragma unroll
            for (int nt = 0; nt < 4; ++nt) {
                int n = n0 + wn * 64 + nt * 16 + ln;
                int h = n >> 6, d = n & 63;
                half4v pv = pack4(acc[mt][nt][0], acc[mt][nt][1],
                                  acc[mt][nt][2], acc[mt][nt][3]);
                *(half4v*)&vtOut[((size_t)(b * HH + h) * HD + d) * SS + s0] = pv;
            }
        }
    }
}

// ---------------- Flash attention, S^T orientation ----------------
// 512 threads = 8 waves; AI=128 (16 i per wave), AJ=64 j-tile.
#define AI 128
#define AJ 64
__global__ __launch_bounds__(512, 4) void attn_mfma(const _Float16* __restrict__ qh,
                                                    const _Float16* __restrict__ kh,
                                                    const _Float16* __restrict__ vt,
                                                    float* __restrict__ out) {
    __shared__ __align__(16) _Float16 Qt[AJ * HD];   // 64 j-rows x 64 d (swizzled)
    __shared__ __align__(16) _Float16 Vs[HD * AJ];   // 64 d-rows x 64 j (swizzled)
    __shared__ __align__(16) _Float16 Ps[AI * AJ];   // 128 i-rows x 64 j (wave-private)
    int t = threadIdx.x, w = t >> 6, lane = t & 63, q = lane >> 4, ln = lane & 15;
    int i0 = blockIdx.x * AI;
    int bh = blockIdx.y, b = bh >> 3, h = bh & 7;
    const _Float16* Kb = kh + (size_t)bh * SS * HD;
    const _Float16* Qb = qh + (size_t)bh * SS * HD;
    const _Float16* Vb = vt + (size_t)bh * HD * SS;

    // K fragments (B-operand): row i = i0 + w*16 + ln, held in regs for all j
    half8v kf[2];
    #pragma unroll
    for (int kk = 0; kk < 2; ++kk)
        kf[kk] = *(const half8v*)&Kb[(size_t)(i0 + w * 16 + ln) * HD + kk * 32 + q * 8];

    f32x4 oacc[4], lacc;
    float m_run = -3.0e38f;
    lacc = (f32x4){0.f, 0.f, 0.f, 0.f};
    #pragma unroll
    for (int mtd = 0; mtd < 4; ++mtd) oacc[mtd] = (f32x4){0.f, 0.f, 0.f, 0.f};
    half8v ones;
    #pragma unroll
    for (int e = 0; e < 8; ++e) ones[e] = (_Float16)1.0f;
    const f32x4 zf = (f32x4){0.f, 0.f, 0.f, 0.f};

    // staging indices: each thread stages one 16B chunk of Qt and one of Vs
    int sr = t >> 3;          // 0..63 (row)
    int sc = t & 7;           // chunk slot
    int ssw = sc ^ (sr & 7);  // swizzled source chunk

    for (int j0 = 0; j0 < SS; j0 += AJ) {
        gload_lds16(Qb + (size_t)(j0 + sr) * HD + ssw * 8, Qt + (size_t)w * 64 * 8);
        gload_lds16(Vb + (size_t)sr * SS + j0 + ssw * 8,   Vs + (size_t)w * 64 * 8);
        __syncthreads();

        // ---- S^T = Q.K^T : M=j(64), N=i(16/wave), K=d(64) ----
        f32x4 sacc[4];
        #pragma unroll
        for (int mt = 0; mt < 4; ++mt) {
            half8v qf = *(half8v*)&Qt[(mt * 16 + ln) * HD + (q ^ (ln & 7)) * 8];
            sacc[mt] = __builtin_amdgcn_mfma_f32_16x16x32_f16(qf, kf[0], zf, 0, 0, 0);
        }
        #pragma unroll
        for (int mt = 0; mt < 4; ++mt) {
            half8v qf = *(half8v*)&Qt[(mt * 16 + ln) * HD + ((4 + q) ^ (ln & 7)) * 8];
            sacc[mt] = __builtin_amdgcn_mfma_f32_16x16x32_f16(qf, kf[1], sacc[mt], 0, 0, 0);
        }

        // ---- online softmax over j (row axis; 16 local + 2 shuffles) ----
        float mx = sacc[0][0];
        #pragma unroll
        for (int mt = 0; mt < 4; ++mt)
            #pragma unroll
            for (int r = 0; r < 4; ++r) mx = fmaxf(mx, sacc[mt][r]);
        mx = fmaxf(mx, __shfl_xor(mx, 16));
        mx = fmaxf(mx, __shfl_xor(mx, 32));
        float mn = fmaxf(m_run, mx);
        if (__any(mn > m_run)) {
            float a = fast_exp2(m_run - mn);
            lacc *= a;
            #pragma unroll
            for (int mtd = 0; mtd < 4; ++mtd) oacc[mtd] *= a;
        }
        m_run = mn;

        // ---- P = exp2(S^T - m) -> wave-private LDS rows (no barrier) ----
        int rp = w * 16 + ln;
        #pragma unroll
        for (int mt = 0; mt < 4; ++mt) {
            float p0 = fast_exp2(sacc[mt][0] - mn);
            float p1 = fast_exp2(sacc[mt][1] - mn);
            float p2 = fast_exp2(sacc[mt][2] - mn);
            float p3 = fast_exp2(sacc[mt][3] - mn);
            int cw = mt * 2 + (q >> 1);
            int pos = cw ^ (ln & 7);
            *(half4v*)&Ps[(size_t)rp * AJ + pos * 8 + (q & 1) * 4] =
                pack4(p0, p1, p2, p3);
        }

        // ---- O^T += V^T.P^T ; l += 1.P^T  (M=d, N=i, K=j) ----
        #pragma unroll
        for (int ks = 0; ks < 2; ++ks) {
            int pos = ((ks * 4 + q) ^ (ln & 7)) * 8;
            half8v pf = *(half8v*)&Ps[(size_t)(w * 16 + ln) * AJ + pos];
            lacc = __builtin_amdgcn_mfma_f32_16x16x32_f16(ones, pf, lacc, 0, 0, 0);
            #pragma unroll
            for (int mtd = 0; mtd < 4; ++mtd) {
                half8v vf = *(half8v*)&Vs[(size_t)(mtd * 16 + ln) * AJ + pos];
                oacc[mtd] = __builtin_amdgcn_mfma_f32_16x16x32_f16(vf, pf, oacc[mtd], 0, 0, 0);
            }
        }
        __syncthreads();   // Qt/Vs overwritten next iter
    }

    // ---- epilogue: O[i][d] = O^T[d][i] / l ----
    float inv = 1.0f / lacc[0];
    int i = i0 + w * 16 + ln;
    #pragma unroll
    for (int mtd = 0; mtd < 4; ++mtd) {
        float4 o;
        o.x = oacc[mtd][0] * inv;
        o.y = oacc[mtd][1] * inv;
        o.z = oacc[mtd][2] * inv;
        o.w = oacc[mtd][3] * inv;
        *(float4*)&out[(size_t)(b * SS + i) * DD + h * HD + mtd * 16 + q * 4] = o;
    }
}

extern "C" void kernel_launch(void* const* d_in, const int* in_sizes, int n_in,
                              void* d_out, int out_size, void* d_ws, size_t ws_size,
                              hipStream_t stream) {
    const float* seq_k = (const float*)d_in[0];
    const float* seq_q = (const float*)d_in[1];
    const float* seq_v = (const float*)d_in[2];
    const float* W1    = (const float*)d_in[3];
    const float* W2    = (const float*)d_in[4];
    const float* W3    = (const float*)d_in[5];
    const float* gamma = (const float*)d_in[6];
    const float* beta  = (const float*)d_in[7];
    float* out = (float*)d_out;

    const size_t MB = 1024 * 1024;
    char* w8 = (char*)d_ws;
    float*    v_in = (float*)w8;                    // [0,16) MB fp32 residual
    _Float16* a16  = (_Float16*)(w8 + 16 * MB);     // q16,k16,v16 [16,40)
    _Float16* w16  = (_Float16*)(w8 + 40 * MB);     // [40,42)
    _Float16* qh   = (_Float16*)(w8 + 48 * MB);     // [48,56)
    _Float16* vt   = (_Float16*)(w8 + 64 * MB);     // [64,72)
    float*    ao   = (float*)(w8 + 16 * MB);        // aliases a16/w16 (dead post-gemm)

    _Float16* q16 = a16;                // q,k contiguous for fused cast
    _Float16* v16 = a16 + 2 * NE;
    _Float16* kh  = qh + NE;

    // 1. fused prep: LN(seq_v) + cast q/k + cast W (W1 pre-scaled by log2e)
    hipLaunchKernelGGL(prep_kernel, dim3(2 * NTOK + 768), dim3(256), 0, stream,
                       seq_v, seq_q, seq_k, W1, W2, W3, gamma, beta,
                       v_in, v16, q16, w16);
    // 2. projections: q,k -> head-split; v -> transposed vt directly
    hipLaunchKernelGGL(gemm_mfma, dim3(DD / GBN, NTOK / GBM, 3), dim3(256), 0, stream,
                       a16, w16, qh, vt);
    // 3. flash attention
    hipLaunchKernelGGL(attn_mfma, dim3(SS / AI, BB * HH), dim3(512), 0, stream,
                       qh, kh, vt, ao);
    // 4. residual + final LN
    hipLaunchKernelGGL(ln_kernel, dim3(NTOK), dim3(256), 0, stream,
                       ao, v_in, gamma, beta, out);
}

// Round 7
// 196.024 us; speedup vs baseline: 1.1907x; 1.0049x over previous
//
#include <hip/hip_runtime.h>
#include <math.h>

#define BB 4
#define SS 2048
#define DD 512
#define HH 8
#define HD 64
#define NTOK (BB*SS)
#define EPS 1e-5f
#define NE ((size_t)NTOK * DD)
#define WN ((size_t)DD * DD)
#define LOG2E 1.4426950408889634f

typedef _Float16 half8v __attribute__((ext_vector_type(8)));
typedef _Float16 half4v __attribute__((ext_vector_type(4)));
typedef _Float16 half2v __attribute__((ext_vector_type(2)));
typedef float f32x4 __attribute__((ext_vector_type(4)));

__device__ __forceinline__ float fast_exp2(float x) {
#if __has_builtin(__builtin_amdgcn_exp2f)
    return __builtin_amdgcn_exp2f(x);
#else
    return __expf(x * 0.6931471805599453f);
#endif
}

__device__ __forceinline__ half2v pack2(float a, float b) {
    return __builtin_bit_cast(half2v, __builtin_amdgcn_cvt_pkrtz(a, b));
}

__device__ __forceinline__ half4v pack4(float a, float b, float c, float d) {
    half2v lo = pack2(a, b);
    half2v hi = pack2(c, d);
    half4v r; r[0] = lo[0]; r[1] = lo[1]; r[2] = hi[0]; r[3] = hi[1];
    return r;
}

__device__ __forceinline__ void gload_lds16(const void* g, void* l) {
    __builtin_amdgcn_global_load_lds(
        (const __attribute__((address_space(1))) unsigned int*)g,
        (__attribute__((address_space(3))) unsigned int*)l, 16, 0, 0);
}

// ---------------- final LayerNorm (with residual) ----------------
__global__ __launch_bounds__(256) void ln_kernel(const float* __restrict__ x,
                                                 const float* __restrict__ res,
                                                 const float* __restrict__ gamma,
                                                 const float* __restrict__ beta,
                                                 float* __restrict__ y) {
    int row = blockIdx.x;
    const float* xr = x + (size_t)row * DD;
    int t = threadIdx.x;
    float2 v = ((const float2*)xr)[t];
    {
        float2 r = ((const float2*)(res + (size_t)row * DD))[t];
        v.x += r.x; v.y += r.y;
    }
    float s = v.x + v.y;
    float ss = v.x * v.x + v.y * v.y;
    #pragma unroll
    for (int off = 32; off; off >>= 1) {
        s  += __shfl_down(s,  off);
        ss += __shfl_down(ss, off);
    }
    __shared__ float ws0[4], ws1[4];
    int wid = t >> 6, lane = t & 63;
    if (lane == 0) { ws0[wid] = s; ws1[wid] = ss; }
    __syncthreads();
    __shared__ float mu_s, rstd_s;
    if (t == 0) {
        float S0 = ws0[0] + ws0[1] + ws0[2] + ws0[3];
        float S1 = ws1[0] + ws1[1] + ws1[2] + ws1[3];
        float mu = S0 * (1.0f / DD);
        float var = S1 * (1.0f / DD) - mu * mu;
        mu_s = mu;
        rstd_s = rsqrtf(var + EPS);
    }
    __syncthreads();
    float mu = mu_s, rstd = rstd_s;
    float2 g = ((const float2*)gamma)[t];
    float2 bb = ((const float2*)beta)[t];
    float2 o;
    o.x = (v.x - mu) * rstd * g.x + bb.x;
    o.y = (v.y - mu) * rstd * g.y + bb.y;
    ((float2*)(y + (size_t)row * DD))[t] = o;
}

// ---------------- prep: LN(seq_v) + cast q/k + cast W (fused) --------------
__global__ __launch_bounds__(256) void prep_kernel(const float* __restrict__ seq_v,
                                                   const float* __restrict__ seq_q,
                                                   const float* __restrict__ seq_k,
                                                   const float* __restrict__ W1,
                                                   const float* __restrict__ W2,
                                                   const float* __restrict__ W3,
                                                   const float* __restrict__ gamma,
                                                   const float* __restrict__ beta,
                                                   float* __restrict__ v_in,
                                                   _Float16* __restrict__ v16,
                                                   _Float16* __restrict__ qk16,
                                                   _Float16* __restrict__ w16) {
    int bid = blockIdx.x;
    int t = threadIdx.x;
    if (bid < NTOK) {
        int row = bid;
        float2 v = ((const float2*)(seq_v + (size_t)row * DD))[t];
        float s = v.x + v.y;
        float ss = v.x * v.x + v.y * v.y;
        #pragma unroll
        for (int off = 32; off; off >>= 1) {
            s  += __shfl_down(s,  off);
            ss += __shfl_down(ss, off);
        }
        __shared__ float ws0[4], ws1[4];
        int wid = t >> 6, lane = t & 63;
        if (lane == 0) { ws0[wid] = s; ws1[wid] = ss; }
        __syncthreads();
        __shared__ float mu_s, rstd_s;
        if (t == 0) {
            float S0 = ws0[0] + ws0[1] + ws0[2] + ws0[3];
            float S1 = ws1[0] + ws1[1] + ws1[2] + ws1[3];
            float mu = S0 * (1.0f / DD);
            float var = S1 * (1.0f / DD) - mu * mu;
            mu_s = mu;
            rstd_s = rsqrtf(var + EPS);
        }
        __syncthreads();
        float mu = mu_s, rstd = rstd_s;
        float2 g = ((const float2*)gamma)[t];
        float2 bb = ((const float2*)beta)[t];
        float2 o;
        o.x = (v.x - mu) * rstd * g.x + bb.x;
        o.y = (v.y - mu) * rstd * g.y + bb.y;
        ((float2*)(v_in + (size_t)row * DD))[t] = o;
        *(half2v*)&v16[(size_t)row * DD + 2 * t] = pack2(o.x, o.y);
    } else if (bid < 2 * NTOK) {
        size_t i = ((size_t)(bid - NTOK) * 256 + t) * 4;
        const float* src = (i < NE) ? (seq_q + i) : (seq_k + (i - NE));
        float4 v = *(const float4*)src;
        *(half4v*)(qk16 + i) = pack4(v.x, v.y, v.z, v.w);
    } else {
        size_t i = ((size_t)(bid - 2 * NTOK) * 256 + t) * 4;
        const float* src; float sc;
        if (i < WN)          { src = W1 + i;            sc = LOG2E; }
        else if (i < 2 * WN) { src = W2 + (i - WN);     sc = 1.0f; }
        else                 { src = W3 + (i - 2 * WN); sc = 1.0f; }
        float4 v = *(const float4*)src;
        *(half4v*)(w16 + i) = pack4(v.x * sc, v.y * sc, v.z * sc, v.w * sc);
    }
}

// ---------------- MFMA GEMM: all three projections in one launch ------------
#define GBM 128
#define GBN 128
#define GBK 64
__global__ __launch_bounds__(256) void gemm_mfma(const _Float16* __restrict__ Aall,
                                                 const _Float16* __restrict__ Wall,
                                                 _Float16* __restrict__ Call,
                                                 _Float16* __restrict__ vtOut) {
    __shared__ __align__(16) _Float16 As[GBM * GBK];
    __shared__ __align__(16) _Float16 Ws[GBN * GBK];
    int z = blockIdx.z;
    bool isv = (z == 2);
    const _Float16* A = Aall + (size_t)z * NE;
    const _Float16* W = Wall + (size_t)z * WN;
    int t = threadIdx.x, w = t >> 6, lane = t & 63, q = lane >> 4, ln = lane & 15;
    int lrow = lane >> 3, lseg = lane & 7;
    int m0 = blockIdx.y * GBM, n0 = blockIdx.x * GBN;
    int wm = w & 1, wn = w >> 1;
    f32x4 acc[4][4];
    #pragma unroll
    for (int mt = 0; mt < 4; ++mt)
        #pragma unroll
        for (int nt = 0; nt < 4; ++nt)
            acc[mt][nt] = (f32x4){0.f, 0.f, 0.f, 0.f};

    int gs = lseg ^ lrow;
    for (int k0 = 0; k0 < DD; k0 += GBK) {
        #pragma unroll
        for (int p = 0; p < 4; ++p) {
            int r = w * 32 + p * 8 + lrow;
            gload_lds16(A + (size_t)(m0 + r) * DD + k0 + gs * 8,
                        As + (size_t)(w * 32 + p * 8) * GBK);
            gload_lds16(W + (size_t)(n0 + r) * DD + k0 + gs * 8,
                        Ws + (size_t)(w * 32 + p * 8) * GBK);
        }
        __syncthreads();
        #pragma unroll
        for (int kk = 0; kk < 2; ++kk) {
            int ch = ((4 * kk + q) ^ (ln & 7)) * 8;
            half8v af[4], wf[4];
            #pragma unroll
            for (int mt = 0; mt < 4; ++mt)
                af[mt] = *(half8v*)&As[(wm * 64 + mt * 16 + ln) * GBK + ch];
            #pragma unroll
            for (int nt = 0; nt < 4; ++nt)
                wf[nt] = *(half8v*)&Ws[(wn * 64 + nt * 16 + ln) * GBK + ch];
            if (!isv) {
                #pragma unroll
                for (int mt = 0; mt < 4; ++mt)
                    #pragma unroll
                    for (int nt = 0; nt < 4; ++nt)
                        acc[mt][nt] = __builtin_amdgcn_mfma_f32_16x16x32_f16(
                            wf[nt], af[mt], acc[mt][nt], 0, 0, 0);  // C^T
            } else {
                #pragma unroll
                for (int mt = 0; mt < 4; ++mt)
                    #pragma unroll
                    for (int nt = 0; nt < 4; ++nt)
                        acc[mt][nt] = __builtin_amdgcn_mfma_f32_16x16x32_f16(
                            af[mt], wf[nt], acc[mt][nt], 0, 0, 0);  // C
            }
        }
        __syncthreads();
    }
    if (!isv) {
        _Float16* C = Call + (size_t)z * NE;
        #pragma unroll
        for (int mt = 0; mt < 4; ++mt) {
            int m = m0 + wm * 64 + mt * 16 + ln;
            int b = m >> 11, s = m & (SS - 1);
            #pragma unroll
            for (int nt = 0; nt < 4; ++nt) {
                int nb = n0 + wn * 64 + nt * 16 + q * 4;
                int h = nb >> 6, d0 = nb & 63;
                half4v pv = pack4(acc[mt][nt][0], acc[mt][nt][1],
                                  acc[mt][nt][2], acc[mt][nt][3]);
                *(half4v*)&C[((size_t)(b * HH + h) * SS + s) * HD + d0] = pv;
            }
        }
    } else {
        #pragma unroll
        for (int mt = 0; mt < 4; ++mt) {
            int mb = m0 + wm * 64 + mt * 16 + q * 4;
            int b = mb >> 11, s0 = mb & (SS - 1);
            #pragma unroll
            for (int nt = 0; nt < 4; ++nt) {
                int n = n0 + wn * 64 + nt * 16 + ln;
                int h = n >> 6, d = n & 63;
                half4v pv = pack4(acc[mt][nt][0], acc[mt][nt][1],
                                  acc[mt][nt][2], acc[mt][nt][3]);
                *(half4v*)&vtOut[((size_t)(b * HH + h) * HD + d) * SS + s0] = pv;
            }
        }
    }
}

// ---------------- Flash attention, S^T orientation, double-buffered --------
// 512 threads = 8 waves; AI=128 (16 i per wave), AJ=64 j-tile.
// K-loop: ONE barrier per iter; next tile's global_load_lds issued right
// after the barrier so the next barrier's vmcnt(0) drain is ~free.
#define AI 128
#define AJ 64
__global__ __launch_bounds__(512, 4) void attn_mfma(const _Float16* __restrict__ qh,
                                                    const _Float16* __restrict__ kh,
                                                    const _Float16* __restrict__ vt,
                                                    float* __restrict__ out) {
    __shared__ __align__(16) _Float16 Qt[2][AJ * HD];   // 64 j x 64 d (swizzled)
    __shared__ __align__(16) _Float16 Vs[2][HD * AJ];   // 64 d x 64 j (swizzled)
    __shared__ __align__(16) _Float16 Ps[AI * AJ];      // wave-private P rows
    int t = threadIdx.x, w = t >> 6, lane = t & 63, q = lane >> 4, ln = lane & 15;
    int i0 = blockIdx.x * AI;
    int bh = blockIdx.y, b = bh >> 3, h = bh & 7;
    const _Float16* Kb = kh + (size_t)bh * SS * HD;
    const _Float16* Qb = qh + (size_t)bh * SS * HD;
    const _Float16* Vb = vt + (size_t)bh * HD * SS;

    // K fragments (B-operand): row i = i0 + w*16 + ln, in regs for all j
    half8v kf[2];
    #pragma unroll
    for (int kk = 0; kk < 2; ++kk)
        kf[kk] = *(const half8v*)&Kb[(size_t)(i0 + w * 16 + ln) * HD + kk * 32 + q * 8];

    f32x4 oacc[4], lacc;
    float m_run = -3.0e38f;
    lacc = (f32x4){0.f, 0.f, 0.f, 0.f};
    #pragma unroll
    for (int mtd = 0; mtd < 4; ++mtd) oacc[mtd] = (f32x4){0.f, 0.f, 0.f, 0.f};
    half8v ones;
    #pragma unroll
    for (int e = 0; e < 8; ++e) ones[e] = (_Float16)1.0f;
    const f32x4 zf = (f32x4){0.f, 0.f, 0.f, 0.f};

    // staging: each thread stages one 16B chunk of Qt and one of Vs
    int sr = t >> 3;          // 0..63 (row)
    int sc = t & 7;           // chunk slot
    int ssw = sc ^ (sr & 7);  // swizzled source chunk

    // prologue: stage tile 0 into buffer 0
    gload_lds16(Qb + (size_t)sr * HD + ssw * 8, &Qt[0][(size_t)w * 512]);
    gload_lds16(Vb + (size_t)sr * SS + ssw * 8, &Vs[0][(size_t)w * 512]);

    const int NITER = SS / AJ;
    for (int jt = 0; jt < NITER; ++jt) {
        int cur = jt & 1;
        __syncthreads();   // drains vmcnt -> buffer `cur` ready; prior reads done

        // prefetch next tile into the other buffer (in flight during compute)
        if (jt + 1 < NITER) {
            int j1 = (jt + 1) * AJ;
            gload_lds16(Qb + (size_t)(j1 + sr) * HD + ssw * 8, &Qt[cur ^ 1][(size_t)w * 512]);
            gload_lds16(Vb + (size_t)sr * SS + j1 + ssw * 8,   &Vs[cur ^ 1][(size_t)w * 512]);
        }

        // ---- S^T = Q.K^T : M=j(64), N=i(16/wave), K=d(64) ----
        f32x4 sacc[4];
        #pragma unroll
        for (int mt = 0; mt < 4; ++mt) {
            half8v qf = *(half8v*)&Qt[cur][(mt * 16 + ln) * HD + (q ^ (ln & 7)) * 8];
            sacc[mt] = __builtin_amdgcn_mfma_f32_16x16x32_f16(qf, kf[0], zf, 0, 0, 0);
        }
        #pragma unroll
        for (int mt = 0; mt < 4; ++mt) {
            half8v qf = *(half8v*)&Qt[cur][(mt * 16 + ln) * HD + ((4 + q) ^ (ln & 7)) * 8];
            sacc[mt] = __builtin_amdgcn_mfma_f32_16x16x32_f16(qf, kf[1], sacc[mt], 0, 0, 0);
        }

        // ---- online softmax over j (row axis; 16 local + 2 shuffles) ----
        float mx = sacc[0][0];
        #pragma unroll
        for (int mt = 0; mt < 4; ++mt)
            #pragma unroll
            for (int r = 0; r < 4; ++r) mx = fmaxf(mx, sacc[mt][r]);
        mx = fmaxf(mx, __shfl_xor(mx, 16));
        mx = fmaxf(mx, __shfl_xor(mx, 32));
        float mn = fmaxf(m_run, mx);
        if (__any(mn > m_run)) {
            float a = fast_exp2(m_run - mn);
            lacc *= a;
            #pragma unroll
            for (int mtd = 0; mtd < 4; ++mtd) oacc[mtd] *= a;
        }
        m_run = mn;

        // ---- P = exp2(S^T - m) -> wave-private LDS rows (no barrier) ----
        int rp = w * 16 + ln;
        #pragma unroll
        for (int mt = 0; mt < 4; ++mt) {
            float p0 = fast_exp2(sacc[mt][0] - mn);
            float p1 = fast_exp2(sacc[mt][1] - mn);
            float p2 = fast_exp2(sacc[mt][2] - mn);
            float p3 = fast_exp2(sacc[mt][3] - mn);
            int cw = mt * 2 + (q >> 1);
            int pos = cw ^ (ln & 7);
            *(half4v*)&Ps[(size_t)rp * AJ + pos * 8 + (q & 1) * 4] =
                pack4(p0, p1, p2, p3);
        }

        // ---- O^T += V^T.P^T ; l += 1.P^T  (M=d, N=i, K=j) ----
        #pragma unroll
        for (int ks = 0; ks < 2; ++ks) {
            int pos = ((ks * 4 + q) ^ (ln & 7)) * 8;
            half8v pf = *(half8v*)&Ps[(size_t)(w * 16 + ln) * AJ + pos];
            lacc = __builtin_amdgcn_mfma_f32_16x16x32_f16(ones, pf, lacc, 0, 0, 0);
            #pragma unroll
            for (int mtd = 0; mtd < 4; ++mtd) {
                half8v vf = *(half8v*)&Vs[cur][(size_t)(mtd * 16 + ln) * AJ + pos];
                oacc[mtd] = __builtin_amdgcn_mfma_f32_16x16x32_f16(vf, pf, oacc[mtd], 0, 0, 0);
            }
        }
    }

    // ---- epilogue: O[i][d] = O^T[d][i] / l ----
    float inv = 1.0f / lacc[0];
    int i = i0 + w * 16 + ln;
    #pragma unroll
    for (int mtd = 0; mtd < 4; ++mtd) {
        float4 o;
        o.x = oacc[mtd][0] * inv;
        o.y = oacc[mtd][1] * inv;
        o.z = oacc[mtd][2] * inv;
        o.w = oacc[mtd][3] * inv;
        *(float4*)&out[(size_t)(b * SS + i) * DD + h * HD + mtd * 16 + q * 4] = o;
    }
}

extern "C" void kernel_launch(void* const* d_in, const int* in_sizes, int n_in,
                              void* d_out, int out_size, void* d_ws, size_t ws_size,
                              hipStream_t stream) {
    const float* seq_k = (const float*)d_in[0];
    const float* seq_q = (const float*)d_in[1];
    const float* seq_v = (const float*)d_in[2];
    const float* W1    = (const float*)d_in[3];
    const float* W2    = (const float*)d_in[4];
    const float* W3    = (const float*)d_in[5];
    const float* gamma = (const float*)d_in[6];
    const float* beta  = (const float*)d_in[7];
    float* out = (float*)d_out;

    const size_t MB = 1024 * 1024;
    char* w8 = (char*)d_ws;
    float*    v_in = (float*)w8;                    // [0,16) MB fp32 residual
    _Float16* a16  = (_Float16*)(w8 + 16 * MB);     // q16,k16,v16 [16,40)
    _Float16* w16  = (_Float16*)(w8 + 40 * MB);     // [40,42)
    _Float16* qh   = (_Float16*)(w8 + 48 * MB);     // [48,56)
    _Float16* vt   = (_Float16*)(w8 + 64 * MB);     // [64,72)
    float*    ao   = (float*)(w8 + 16 * MB);        // aliases a16/w16 (dead post-gemm)

    _Float16* q16 = a16;                // q,k contiguous for fused cast
    _Float16* v16 = a16 + 2 * NE;
    _Float16* kh  = qh + NE;

    // 1. fused prep: LN(seq_v) + cast q/k + cast W (W1 pre-scaled by log2e)
    hipLaunchKernelGGL(prep_kernel, dim3(2 * NTOK + 768), dim3(256), 0, stream,
                       seq_v, seq_q, seq_k, W1, W2, W3, gamma, beta,
                       v_in, v16, q16, w16);
    // 2. projections: q,k -> head-split; v -> transposed vt directly
    hipLaunchKernelGGL(gemm_mfma, dim3(DD / GBN, NTOK / GBM, 3), dim3(256), 0, stream,
                       a16, w16, qh, vt);
    // 3. flash attention (double-buffered)
    hipLaunchKernelGGL(attn_mfma, dim3(SS / AI, BB * HH), dim3(512), 0, stream,
                       qh, kh, vt, ao);
    // 4. residual + final LN
    hipLaunchKernelGGL(ln_kernel, dim3(NTOK), dim3(256), 0, stream,
                       ao, v_in, gamma, beta, out);
}